// Round 7
// baseline (121.191 us; speedup 1.0000x reference)
//
#include <hip/hip_runtime.h>
#include <hip/hip_bf16.h>

#define SDIM 2048
#define KWIN 20
#define WWIN 41

typedef __attribute__((ext_vector_type(8))) short s8v;
typedef __attribute__((ext_vector_type(4))) float f32x4;
#define MFMA __builtin_amdgcn_mfma_f32_16x16x32_bf16

// ws: V fp32[16][64] @0; BT fp32[16][64] @4096(floats:1024); C fp32[16] @8192(2048);
// MB bf16[16][80][64] @8256 B; WTB bf16[16][64][64] @172096 B
#define WSB_MB 8256
#define WSB_WT 172096

// LDS: read-only after the single barrier. 16576 B -> ~6-7 blocks/CU.
#define O_YJF 0       /* bf16 [112][72] pitch 144 B : Y[j][f] */
#define O_RF  16128   /* fp32 [112] rowflag */
#define LDS_TOTAL 16576

__device__ __forceinline__ int detect_is_bf16(const void* xp) {
  const unsigned* w = (const unsigned*)xp;
  const unsigned word = w[threadIdx.x & 63];
  const unsigned e = (word >> 7) & 0xFFu;
  const unsigned long long m = __ballot(e >= 118u && e <= 132u);
  return __popcll(m) >= 32;
}
__device__ __forceinline__ float ldf(const void* p, size_t i, int isbf) {
  return isbf ? __bfloat162float(((const __hip_bfloat16*)p)[i]) : ((const float*)p)[i];
}
// f32 -> bf16 bits, RNE (finite inputs only)
__device__ __forceinline__ unsigned bfb(float f) {
  union { float f; unsigned u; } x; x.f = f;
  return (x.u + 0x7FFFu + ((x.u >> 16) & 1u)) >> 16;
}
__device__ __forceinline__ int pkbf(float a, float b) {
  return (int)(bfb(a) | (bfb(b) << 16));
}
// C-layout tile pair (m in [0,32)) -> A/B-frag (k=8q+j) via quad shuffles.
__device__ __forceinline__ s8v xform(int p00, int p01, int p10, int p11, int lane) {
  const int q = lane >> 4;
  const int sA = (lane & 15) + ((q & 1) << 5);
  const int sB = sA + 16;
  const bool hi = (q >> 1) != 0;
  const int w0a = __shfl(p00, sA), w0b = __shfl(p10, sA);
  const int w1a = __shfl(p01, sA), w1b = __shfl(p11, sA);
  const int w2a = __shfl(p00, sB), w2b = __shfl(p10, sB);
  const int w3a = __shfl(p01, sB), w3b = __shfl(p11, sB);
  union { int i[4]; s8v v; } u;
  u.i[0] = hi ? w0b : w0a;
  u.i[1] = hi ? w1b : w1a;
  u.i[2] = hi ? w2b : w2a;
  u.i[3] = hi ? w3b : w3a;
  return u.v;
}

__global__ __launch_bounds__(256) void prep_kernel(
    const void* __restrict__ x,
    const void* __restrict__ Wq, const void* __restrict__ bq,
    const void* __restrict__ Wk, const void* __restrict__ bk,
    const void* __restrict__ Wt, const void* __restrict__ bt,
    const int* __restrict__ sip, float* __restrict__ ws) {
  const int isbf = detect_is_bf16(x);
  const int al = blockIdx.x, a = al >> 2, li = al & 3;
  const int fq = blockIdx.y;  // f-quarter
  const int si = *sip;
  int off = 0;
  const int ATTR[5] = {3, 3, 1, 4, 3};
  for (int i = 0; i < si - 1 && i < 5; ++i) off += ATTR[i];
  const size_t wb = ((size_t)(off + a) * 5 + li) * 4096;
  const size_t bb = ((size_t)(off + a) * 5 + li) * 64;
  const int tid = threadIdx.x;

  __shared__ float sq[4096], sk[4096];
  __shared__ float sbq[64], sbk[64];
  for (int i = tid; i < 4096; i += 256) {
    sq[i] = ldf(Wq, wb + i, isbf);
    sk[i] = ldf(Wk, wb + i, isbf);
  }
  if (tid < 64) { sbq[tid] = ldf(bq, bb + tid, isbf); sbk[tid] = ldf(bk, bb + tid, isbf); }
  __syncthreads();

  __hip_bfloat16* mb  = (__hip_bfloat16*)((char*)ws + WSB_MB) + (size_t)al * 5120;
  __hip_bfloat16* wtb = (__hip_bfloat16*)((char*)ws + WSB_WT) + (size_t)al * 4096;

  for (int t = tid; t < 1024; t += 256) {
    const int f = fq * 16 + (t >> 6), f2 = t & 63;
    float acc = 0.f;
    #pragma unroll 16
    for (int g = 0; g < 64; ++g) acc += sk[g * 64 + f] * sq[g * 64 + f2];
    mb[f * 64 + f2] = __float2bfloat16(acc);                    // M[f][f2]
    wtb[f * 64 + f2] = __float2bfloat16(ldf(Wt, wb + f * 64 + f2, isbf));
  }
  if (fq == 0) {
    if (tid < 64) {
      float u = 0.f, v = 0.f;
      for (int g = 0; g < 64; ++g) {
        u += sq[g * 64 + tid] * sbk[g];
        v += sk[g * 64 + tid] * sbq[g];
      }
      mb[64 * 64 + tid] = __float2bfloat16(u);  // row 64 = u
      ws[al * 64 + tid] = v;
      ws[1024 + al * 64 + tid] = ldf(bt, bb + tid, isbf);
    }
    for (int i = tid; i < 15 * 64; i += 256) mb[65 * 64 + i] = __float2bfloat16(0.f);
    if (tid == 0) {
      float c = 0.f;
      for (int g = 0; g < 64; ++g) c += sbq[g] * sbk[g];
      ws[2048 + al] = c;
    }
  }
}

__global__ __launch_bounds__(256) void attn_kernel(
    const void* __restrict__ x, const float* __restrict__ ws,
    float* __restrict__ out) {
  const int isbf = detect_is_bf16(x);
  const int chunk = blockIdx.x;   // 0..31
  const int ba = blockIdx.y;      // b*4 + a
  const int l = blockIdx.z;       // level
  const int b = ba >> 2, a = ba & 3;
  const int s0 = chunk * 64;
  const int tid = threadIdx.x;
  const int lane = tid & 63;
  const int mt = tid >> 6;        // wave = 16-row m-tile
  const int c16 = lane & 15;
  const int q = lane >> 4;

  __shared__ __align__(16) char lds[LDS_TOTAL];

  // ---- stage Y window + rowflags; one barrier ----
  #pragma unroll
  for (int it = 0; it < 7; ++it) {
    const int r = it * 16 + (tid >> 4);   // 0..111
    const int j = s0 - KWIN + r;
    float4 yv = {0.f, 0.f, 0.f, 0.f};
    if (r < 104 && j >= 0 && j < SDIM) {
      if (isbf) {
        const size_t base = (((size_t)b * SDIM + j) * 4 + a) * 64 + c16 * 4;
        yv.x = ldf(x, base, 1); yv.y = ldf(x, base + 1, 1);
        yv.z = ldf(x, base + 2, 1); yv.w = ldf(x, base + 3, 1);
      } else {
        yv = *((const float4*)x + (((size_t)b * SDIM + j) * 4 + a) * 16 + c16);
      }
    }
    const int f0 = c16 * 4;
    ((int*)(lds + O_YJF + r * 144 + f0 * 2))[0] = pkbf(yv.x, yv.y);
    ((int*)(lds + O_YJF + r * 144 + f0 * 2))[1] = pkbf(yv.z, yv.w);
    const bool nz = (yv.x != 0.f) || (yv.y != 0.f) || (yv.z != 0.f) || (yv.w != 0.f);
    const unsigned long long m = __ballot(nz);
    if (c16 == 0) ((float*)(lds + O_RF))[r] = ((m >> (q * 16)) & 0xFFFFull) ? 1.f : 0.f;
  }
  __syncthreads();

  const char* yjf = lds + O_YJF;
  const int al = a * 4 + l;
  const short* mb  = (const short*)((const char*)ws + WSB_MB) + (size_t)al * 5120;
  const short* wtb = (const short*)((const char*)ws + WSB_WT) + (size_t)al * 4096;
  const float c_al = ws[2048 + al];

  // X^T B-frag (query rows), rowflags for own band
  const s8v xb0 = *(const s8v*)(yjf + (KWIN + 16 * mt + c16) * 144 + 16 * q);
  const s8v xb1 = *(const s8v*)(yjf + (KWIN + 16 * mt + c16) * 144 + 64 + 16 * q);
  float rfarr[16];
  #pragma unroll
  for (int nt = 0; nt < 4; ++nt) {
    const float4 t = *(const float4*)((const float*)(lds + O_RF) + 16 * mt + 16 * nt + 4 * q);
    rfarr[nt * 4 + 0] = t.x; rfarr[nt * 4 + 1] = t.y;
    rfarr[nt * 4 + 2] = t.z; rfarr[nt * 4 + 3] = t.w;
  }

  // ===== G1 (swapped): QK^T = M * X^T (+v); m-tile 4 = u-row =====
  int pq[4][2];
  f32x4 uacc = {0.f, 0.f, 0.f, 0.f};
  #pragma unroll
  for (int nt = 0; nt < 5; ++nt) {
    const int rowm = (nt < 4) ? (16 * nt + c16) : (64 + c16);
    const s8v a0 = *(const s8v*)(mb + rowm * 64 + 8 * q);
    const s8v a1 = *(const s8v*)(mb + rowm * 64 + 32 + 8 * q);
    f32x4 acc;
    if (nt < 4) {
      const float4 v4 = *(const float4*)(ws + al * 64 + 16 * nt + 4 * q);
      acc[0] = v4.x; acc[1] = v4.y; acc[2] = v4.z; acc[3] = v4.w;
    } else {
      acc[0] = acc[1] = acc[2] = acc[3] = 0.f;
    }
    acc = MFMA(a0, xb0, acc, 0, 0, 0);
    acc = MFMA(a1, xb1, acc, 0, 0, 0);
    if (nt < 4) { pq[nt][0] = pkbf(acc[0], acc[1]); pq[nt][1] = pkbf(acc[2], acc[3]); }
    else uacc = acc;
  }
  const float ux = __shfl(uacc[0], lane & 15) + c_al;  // u.x for row=c16
  const s8v qb0 = xform(pq[0][0], pq[0][1], pq[1][0], pq[1][1], lane);
  const s8v qb1 = xform(pq[2][0], pq[2][1], pq[3][0], pq[3][1], lane);

  // ===== G2 (swapped): S^T = Y * QK^T ; D[j][row] =====
  f32x4 st[4];
  #pragma unroll
  for (int nt = 0; nt < 4; ++nt) {
    const char* yr = yjf + (16 * mt + 16 * nt + c16) * 144 + 16 * q;
    const s8v a0 = *(const s8v*)yr;
    const s8v a1 = *(const s8v*)(yr + 64);
    f32x4 s = {0.f, 0.f, 0.f, 0.f};
    s = MFMA(a0, qb0, s, 0, 0, 0);
    s = MFMA(a1, qb1, s, 0, 0, 0);
    st[nt] = s;
  }

  // ===== softmax in registers (row = c16, j spread over nt/q/r) =====
  float ee[16];
  float mx = -3.0e38f;
  #pragma unroll
  for (int nt = 0; nt < 4; ++nt)
    #pragma unroll
    for (int r = 0; r < 4; ++r) {
      const int w = 16 * nt + 4 * q + r - c16;
      float lv = -1.0e9f;
      if (w >= 0 && w < WWIN && rfarr[nt * 4 + r] != 0.f)
        lv = (st[nt][r] + ux) * 0.125f;
      ee[nt * 4 + r] = lv;
      mx = fmaxf(mx, lv);
    }
  mx = fmaxf(mx, __shfl_xor(mx, 16));
  mx = fmaxf(mx, __shfl_xor(mx, 32));
  float se = 0.f;
  #pragma unroll
  for (int i = 0; i < 16; ++i) { ee[i] = __expf(ee[i] - mx); se += ee[i]; }
  se += __shfl_xor(se, 16);
  se += __shfl_xor(se, 32);
  const float rse = 1.f / se;

  int pp[4][2];
  #pragma unroll
  for (int nt = 0; nt < 4; ++nt) {
    pp[nt][0] = pkbf(ee[nt * 4 + 0], ee[nt * 4 + 1]);
    pp[nt][1] = pkbf(ee[nt * 4 + 2], ee[nt * 4 + 3]);
  }
  const s8v pb0 = xform(pp[0][0], pp[0][1], pp[1][0], pp[1][1], lane);
  const s8v pb1 = xform(pp[2][0], pp[2][1], pp[3][0], pp[3][1], lane);

  // ===== G3 (swapped): CTX^T = Y^T * P ; A via strided column reads =====
  int cp[4][2];
  #pragma unroll
  for (int nt = 0; nt < 4; ++nt) {
    const char* cbase = yjf + (16 * mt + 8 * q) * 144 + (16 * nt + c16) * 2;
    union { short s[8]; s8v v; } ua0, ua1;
    #pragma unroll
    for (int i = 0; i < 8; ++i) {
      ua0.s[i] = *(const short*)(cbase + i * 144);
      ua1.s[i] = *(const short*)(cbase + (32 + i) * 144);
    }
    f32x4 cc = {0.f, 0.f, 0.f, 0.f};
    cc = MFMA(ua0.v, pb0, cc, 0, 0, 0);
    cc = MFMA(ua1.v, pb1, cc, 0, 0, 0);
    cp[nt][0] = pkbf(cc[0] * rse, cc[1] * rse);
    cp[nt][1] = pkbf(cc[2] * rse, cc[3] * rse);
  }
  const s8v cb0 = xform(cp[0][0], cp[0][1], cp[1][0], cp[1][1], lane);
  const s8v cb1 = xform(cp[2][0], cp[2][1], cp[3][0], cp[3][1], lane);

  // ===== G4 (swapped): OUT^T = Wt * CTX^T + bt ; coalesced dwordx4 store =====
  const int row = 16 * mt + c16;
  float* obase = out + ((((size_t)b * SDIM + s0 + row) * 4 + a) * 4 + l) * 64 + 4 * q;
  #pragma unroll
  for (int nt = 0; nt < 4; ++nt) {
    const s8v a0 = *(const s8v*)(wtb + (16 * nt + c16) * 64 + 8 * q);
    const s8v a1 = *(const s8v*)(wtb + (16 * nt + c16) * 64 + 32 + 8 * q);
    const float4 b4 = *(const float4*)(ws + 1024 + al * 64 + 16 * nt + 4 * q);
    f32x4 o;
    o[0] = b4.x; o[1] = b4.y; o[2] = b4.z; o[3] = b4.w;
    o = MFMA(a0, cb0, o, 0, 0, 0);
    o = MFMA(a1, cb1, o, 0, 0, 0);
    float4 o4; o4.x = o[0]; o4.y = o[1]; o4.z = o[2]; o4.w = o[3];
    *(float4*)(obase + 16 * nt) = o4;
  }
}

extern "C" void kernel_launch(void* const* d_in, const int* in_sizes, int n_in,
                              void* d_out, int out_size, void* d_ws, size_t ws_size,
                              hipStream_t stream) {
  const void* x  = d_in[0];
  const void* Wq = d_in[1];
  const void* bq = d_in[2];
  const void* Wk = d_in[3];
  const void* bk = d_in[4];
  const void* Wt = d_in[5];
  const void* bt = d_in[6];
  const int* sip = (const int*)d_in[7];
  float* ws = (float*)d_ws;
  float* out = (float*)d_out;

  prep_kernel<<<dim3(16, 4), 256, 0, stream>>>(x, Wq, bq, Wk, bk, Wt, bt, sip, ws);
  attn_kernel<<<dim3(32, 16, 4), 256, 0, stream>>>(x, ws, out);
}

// Round 8
// 120.435 us; speedup vs baseline: 1.0063x; 1.0063x over previous
//
#include <hip/hip_runtime.h>
#include <hip/hip_bf16.h>

#define SDIM 2048
#define KWIN 20
#define WWIN 41

typedef __attribute__((ext_vector_type(8))) short s8v;
typedef __attribute__((ext_vector_type(4))) float f32x4;
#define MFMA __builtin_amdgcn_mfma_f32_16x16x32_bf16

// ws: V fp32[16][64] @0; BT fp32[16][64] @4096(floats:1024); C fp32[16] @8192(2048);
// MB bf16[16][80][64] @8256 B; WTB bf16[16][64][64] @172096 B
#define WSB_MB 8256
#define WSB_WT 172096

// LDS (31936 B): read-only after the single barrier -> no fences needed.
#define O_YJF 0       /* bf16 [112][72] pitch 144 B : Y[j][f] */
#define O_YFJ 16128   /* bf16 [64][120] pitch 240 B : Y^T[f][j] */
#define O_RF  31488   /* fp32 [112] rowflag */
#define LDS_TOTAL 31936

__device__ __forceinline__ int detect_is_bf16(const void* xp) {
  const unsigned* w = (const unsigned*)xp;
  const unsigned word = w[threadIdx.x & 63];
  const unsigned e = (word >> 7) & 0xFFu;
  const unsigned long long m = __ballot(e >= 118u && e <= 132u);
  return __popcll(m) >= 32;
}
__device__ __forceinline__ float ldf(const void* p, size_t i, int isbf) {
  return isbf ? __bfloat162float(((const __hip_bfloat16*)p)[i]) : ((const float*)p)[i];
}
// f32 -> bf16 bits, RNE (finite inputs only)
__device__ __forceinline__ unsigned bfb(float f) {
  union { float f; unsigned u; } x; x.f = f;
  return (x.u + 0x7FFFu + ((x.u >> 16) & 1u)) >> 16;
}
__device__ __forceinline__ int pkbf(float a, float b) {
  return (int)(bfb(a) | (bfb(b) << 16));
}
// C-layout tile pair (m in [0,32)) -> A/B-frag (k=8q+j) via quad shuffles.
__device__ __forceinline__ s8v xform(int p00, int p01, int p10, int p11, int lane) {
  const int q = lane >> 4;
  const int sA = (lane & 15) + ((q & 1) << 5);
  const int sB = sA + 16;
  const bool hi = (q >> 1) != 0;
  const int w0a = __shfl(p00, sA), w0b = __shfl(p10, sA);
  const int w1a = __shfl(p01, sA), w1b = __shfl(p11, sA);
  const int w2a = __shfl(p00, sB), w2b = __shfl(p10, sB);
  const int w3a = __shfl(p01, sB), w3b = __shfl(p11, sB);
  union { int i[4]; s8v v; } u;
  u.i[0] = hi ? w0b : w0a;
  u.i[1] = hi ? w1b : w1a;
  u.i[2] = hi ? w2b : w2a;
  u.i[3] = hi ? w3b : w3a;
  return u.v;
}

__global__ __launch_bounds__(256) void prep_kernel(
    const void* __restrict__ x,
    const void* __restrict__ Wq, const void* __restrict__ bq,
    const void* __restrict__ Wk, const void* __restrict__ bk,
    const void* __restrict__ Wt, const void* __restrict__ bt,
    const int* __restrict__ sip, float* __restrict__ ws) {
  const int isbf = detect_is_bf16(x);
  const int al = blockIdx.x, a = al >> 2, li = al & 3;
  const int fq = blockIdx.y;  // f-quarter
  const int si = *sip;
  int off = 0;
  const int ATTR[5] = {3, 3, 1, 4, 3};
  for (int i = 0; i < si - 1 && i < 5; ++i) off += ATTR[i];
  const size_t wb = ((size_t)(off + a) * 5 + li) * 4096;
  const size_t bb = ((size_t)(off + a) * 5 + li) * 64;
  const int tid = threadIdx.x;

  __shared__ float sq[4096], sk[4096];
  __shared__ float sbq[64], sbk[64];
  for (int i = tid; i < 4096; i += 256) {
    sq[i] = ldf(Wq, wb + i, isbf);
    sk[i] = ldf(Wk, wb + i, isbf);
  }
  if (tid < 64) { sbq[tid] = ldf(bq, bb + tid, isbf); sbk[tid] = ldf(bk, bb + tid, isbf); }
  __syncthreads();

  __hip_bfloat16* mb  = (__hip_bfloat16*)((char*)ws + WSB_MB) + (size_t)al * 5120;
  __hip_bfloat16* wtb = (__hip_bfloat16*)((char*)ws + WSB_WT) + (size_t)al * 4096;

  for (int t = tid; t < 1024; t += 256) {
    const int f = fq * 16 + (t >> 6), f2 = t & 63;
    float acc = 0.f;
    #pragma unroll 16
    for (int g = 0; g < 64; ++g) acc += sk[g * 64 + f] * sq[g * 64 + f2];
    mb[f * 64 + f2] = __float2bfloat16(acc);                    // M[f][f2]
    wtb[f * 64 + f2] = __float2bfloat16(ldf(Wt, wb + f * 64 + f2, isbf));
  }
  if (fq == 0) {
    if (tid < 64) {
      float u = 0.f, v = 0.f;
      for (int g = 0; g < 64; ++g) {
        u += sq[g * 64 + tid] * sbk[g];
        v += sk[g * 64 + tid] * sbq[g];
      }
      mb[64 * 64 + tid] = __float2bfloat16(u);  // row 64 = u
      ws[al * 64 + tid] = v;
      ws[1024 + al * 64 + tid] = ldf(bt, bb + tid, isbf);
    }
    for (int i = tid; i < 15 * 64; i += 256) mb[65 * 64 + i] = __float2bfloat16(0.f);
    if (tid == 0) {
      float c = 0.f;
      for (int g = 0; g < 64; ++g) c += sbq[g] * sbk[g];
      ws[2048 + al] = c;
    }
  }
}

__global__ __launch_bounds__(256) void attn_kernel(
    const void* __restrict__ x, const float* __restrict__ ws,
    float* __restrict__ out) {
  const int isbf = detect_is_bf16(x);
  const int chunk = blockIdx.x;   // 0..31
  const int ba = blockIdx.y;      // b*4 + a
  const int b = ba >> 2, a = ba & 3;
  const int s0 = chunk * 64;
  const int tid = threadIdx.x;
  const int lane = tid & 63;
  const int mt = tid >> 6;        // wave = 16-row m-tile
  const int c16 = lane & 15;
  const int q = lane >> 4;

  __shared__ __align__(16) char lds[LDS_TOTAL];

  // ---- stage Y window (both orientations) + rowflags; one barrier ----
  #pragma unroll
  for (int it = 0; it < 7; ++it) {
    const int r = it * 16 + (tid >> 4);   // 0..111
    const int j = s0 - KWIN + r;
    float4 yv = {0.f, 0.f, 0.f, 0.f};
    if (r < 104 && j >= 0 && j < SDIM) {
      if (isbf) {
        const size_t base = (((size_t)b * SDIM + j) * 4 + a) * 64 + c16 * 4;
        yv.x = ldf(x, base, 1); yv.y = ldf(x, base + 1, 1);
        yv.z = ldf(x, base + 2, 1); yv.w = ldf(x, base + 3, 1);
      } else {
        yv = *((const float4*)x + (((size_t)b * SDIM + j) * 4 + a) * 16 + c16);
      }
    }
    const int f0 = c16 * 4;
    ((int*)(lds + O_YJF + r * 144 + f0 * 2))[0] = pkbf(yv.x, yv.y);
    ((int*)(lds + O_YJF + r * 144 + f0 * 2))[1] = pkbf(yv.z, yv.w);
    *(unsigned short*)(lds + O_YFJ + (f0 + 0) * 240 + r * 2) = (unsigned short)bfb(yv.x);
    *(unsigned short*)(lds + O_YFJ + (f0 + 1) * 240 + r * 2) = (unsigned short)bfb(yv.y);
    *(unsigned short*)(lds + O_YFJ + (f0 + 2) * 240 + r * 2) = (unsigned short)bfb(yv.z);
    *(unsigned short*)(lds + O_YFJ + (f0 + 3) * 240 + r * 2) = (unsigned short)bfb(yv.w);
    const bool nz = (yv.x != 0.f) || (yv.y != 0.f) || (yv.z != 0.f) || (yv.w != 0.f);
    const unsigned long long m = __ballot(nz);
    if (c16 == 0) ((float*)(lds + O_RF))[r] = ((m >> (q * 16)) & 0xFFFFull) ? 1.f : 0.f;
  }
  __syncthreads();

  const short* mbase  = (const short*)((const char*)ws + WSB_MB);
  const short* wtbase = (const short*)((const char*)ws + WSB_WT);
  const char* yjf = lds + O_YJF;
  const char* yfj = lds + O_YFJ;

  // level-invariant: X^T B-frag (query rows), rowflags for own band
  const s8v xb0 = *(const s8v*)(yjf + (KWIN + 16 * mt + c16) * 144 + 16 * q);
  const s8v xb1 = *(const s8v*)(yjf + (KWIN + 16 * mt + c16) * 144 + 64 + 16 * q);
  float rfarr[16];
  #pragma unroll
  for (int nt = 0; nt < 4; ++nt) {
    const float4 t = *(const float4*)((const float*)(lds + O_RF) + 16 * mt + 16 * nt + 4 * q);
    rfarr[nt * 4 + 0] = t.x; rfarr[nt * 4 + 1] = t.y;
    rfarr[nt * 4 + 2] = t.z; rfarr[nt * 4 + 3] = t.w;
  }

  for (int l = 0; l < 4; ++l) {
    const int al = a * 4 + l;
    const short* mb  = mbase + (size_t)al * 5120;
    const short* wtb = wtbase + (size_t)al * 4096;
    const float c_al = ws[2048 + al];

    // ===== G1 (swapped): QK^T = M * X^T (+v); m-tile 4 = u-row =====
    int pq[4][2];
    f32x4 uacc = {0.f, 0.f, 0.f, 0.f};
    #pragma unroll
    for (int nt = 0; nt < 5; ++nt) {
      const int rowm = (nt < 4) ? (16 * nt + c16) : (64 + c16);
      const s8v a0 = *(const s8v*)(mb + rowm * 64 + 8 * q);
      const s8v a1 = *(const s8v*)(mb + rowm * 64 + 32 + 8 * q);
      f32x4 acc;
      if (nt < 4) {
        const float4 v4 = *(const float4*)(ws + al * 64 + 16 * nt + 4 * q);
        acc[0] = v4.x; acc[1] = v4.y; acc[2] = v4.z; acc[3] = v4.w;
      } else {
        acc[0] = acc[1] = acc[2] = acc[3] = 0.f;
      }
      acc = MFMA(a0, xb0, acc, 0, 0, 0);
      acc = MFMA(a1, xb1, acc, 0, 0, 0);
      if (nt < 4) { pq[nt][0] = pkbf(acc[0], acc[1]); pq[nt][1] = pkbf(acc[2], acc[3]); }
      else uacc = acc;
    }
    const float ux = __shfl(uacc[0], lane & 15) + c_al;  // u.x for row=c16
    const s8v qb0 = xform(pq[0][0], pq[0][1], pq[1][0], pq[1][1], lane);
    const s8v qb1 = xform(pq[2][0], pq[2][1], pq[3][0], pq[3][1], lane);

    // ===== G2 (swapped): S^T = Y * QK^T ; D[j][row] =====
    f32x4 st[4];
    #pragma unroll
    for (int nt = 0; nt < 4; ++nt) {
      const char* yr = yjf + (16 * mt + 16 * nt + c16) * 144 + 16 * q;
      const s8v a0 = *(const s8v*)yr;
      const s8v a1 = *(const s8v*)(yr + 64);
      f32x4 s = {0.f, 0.f, 0.f, 0.f};
      s = MFMA(a0, qb0, s, 0, 0, 0);
      s = MFMA(a1, qb1, s, 0, 0, 0);
      st[nt] = s;
    }

    // ===== softmax in registers (row = c16, j spread over nt/q/r) =====
    float ee[16];
    float mx = -3.0e38f;
    #pragma unroll
    for (int nt = 0; nt < 4; ++nt)
      #pragma unroll
      for (int r = 0; r < 4; ++r) {
        const int w = 16 * nt + 4 * q + r - c16;
        float lv = -1.0e9f;
        if (w >= 0 && w < WWIN && rfarr[nt * 4 + r] != 0.f)
          lv = (st[nt][r] + ux) * 0.125f;
        ee[nt * 4 + r] = lv;
        mx = fmaxf(mx, lv);
      }
    mx = fmaxf(mx, __shfl_xor(mx, 16));
    mx = fmaxf(mx, __shfl_xor(mx, 32));
    float se = 0.f;
    #pragma unroll
    for (int i = 0; i < 16; ++i) { ee[i] = __expf(ee[i] - mx); se += ee[i]; }
    se += __shfl_xor(se, 16);
    se += __shfl_xor(se, 32);
    const float rse = 1.f / se;

    int pp[4][2];
    #pragma unroll
    for (int nt = 0; nt < 4; ++nt) {
      pp[nt][0] = pkbf(ee[nt * 4 + 0], ee[nt * 4 + 1]);
      pp[nt][1] = pkbf(ee[nt * 4 + 2], ee[nt * 4 + 3]);
    }
    const s8v pb0 = xform(pp[0][0], pp[0][1], pp[1][0], pp[1][1], lane);
    const s8v pb1 = xform(pp[2][0], pp[2][1], pp[3][0], pp[3][1], lane);

    // ===== G3 (swapped): CTX^T = Y^T * P ; scale by rse =====
    int cp[4][2];
    #pragma unroll
    for (int nt = 0; nt < 4; ++nt) {
      const char* fr = yfj + (16 * nt + c16) * 240 + 32 * mt + 16 * q;
      const s8v a0 = *(const s8v*)fr;
      const s8v a1 = *(const s8v*)(fr + 64);
      f32x4 cc = {0.f, 0.f, 0.f, 0.f};
      cc = MFMA(a0, pb0, cc, 0, 0, 0);
      cc = MFMA(a1, pb1, cc, 0, 0, 0);
      cp[nt][0] = pkbf(cc[0] * rse, cc[1] * rse);
      cp[nt][1] = pkbf(cc[2] * rse, cc[3] * rse);
    }
    const s8v cb0 = xform(cp[0][0], cp[0][1], cp[1][0], cp[1][1], lane);
    const s8v cb1 = xform(cp[2][0], cp[2][1], cp[3][0], cp[3][1], lane);

    // ===== G4 (swapped): OUT^T = Wt * CTX^T + bt ; coalesced dwordx4 store =====
    const int row = 16 * mt + c16;
    float* obase = out + ((((size_t)b * SDIM + s0 + row) * 4 + a) * 4 + l) * 64 + 4 * q;
    #pragma unroll
    for (int nt = 0; nt < 4; ++nt) {
      const s8v a0 = *(const s8v*)(wtb + (16 * nt + c16) * 64 + 8 * q);
      const s8v a1 = *(const s8v*)(wtb + (16 * nt + c16) * 64 + 32 + 8 * q);
      const float4 b4 = *(const float4*)(ws + 1024 + al * 64 + 16 * nt + 4 * q);
      f32x4 o;
      o[0] = b4.x; o[1] = b4.y; o[2] = b4.z; o[3] = b4.w;
      o = MFMA(a0, cb0, o, 0, 0, 0);
      o = MFMA(a1, cb1, o, 0, 0, 0);
      float4 o4; o4.x = o[0]; o4.y = o[1]; o4.z = o[2]; o4.w = o[3];
      *(float4*)(obase + 16 * nt) = o4;
    }
  }
}

extern "C" void kernel_launch(void* const* d_in, const int* in_sizes, int n_in,
                              void* d_out, int out_size, void* d_ws, size_t ws_size,
                              hipStream_t stream) {
  const void* x  = d_in[0];
  const void* Wq = d_in[1];
  const void* bq = d_in[2];
  const void* Wk = d_in[3];
  const void* bk = d_in[4];
  const void* Wt = d_in[5];
  const void* bt = d_in[6];
  const int* sip = (const int*)d_in[7];
  float* ws = (float*)d_ws;
  float* out = (float*)d_out;

  prep_kernel<<<dim3(16, 4), 256, 0, stream>>>(x, Wq, bq, Wk, bk, Wt, bt, sip, ws);
  attn_kernel<<<dim3(32, 16), 256, 0, stream>>>(x, ws, out);
}

// Round 9
// 120.226 us; speedup vs baseline: 1.0080x; 1.0017x over previous
//
#include <hip/hip_runtime.h>
#include <hip/hip_bf16.h>

#define SDIM 2048
#define KWIN 20
#define WWIN 41

typedef __attribute__((ext_vector_type(8))) short s8v;
typedef __attribute__((ext_vector_type(4))) float f32x4;
#define MFMA __builtin_amdgcn_mfma_f32_16x16x32_bf16

// ws: V fp32[16][64] @0; BT fp32[16][64] @4096(floats:1024); C fp32[16] @8192(2048);
// MB bf16[16][80][64] @8256 B; WTB bf16[16][64][64] @172096 B
#define WSB_MB 8256
#define WSB_WT 172096

// LDS (31936 B): read-only after the single barrier -> no fences needed.
#define O_YJF 0       /* bf16 [112][72] pitch 144 B : Y[j][f] */
#define O_YFJ 16128   /* bf16 [64][120] pitch 240 B : Y^T[f][j] */
#define O_RF  31488   /* fp32 [112] rowflag */
#define LDS_TOTAL 31936

__device__ __forceinline__ int detect_is_bf16(const void* xp) {
  const unsigned* w = (const unsigned*)xp;
  const unsigned word = w[threadIdx.x & 63];
  const unsigned e = (word >> 7) & 0xFFu;
  const unsigned long long m = __ballot(e >= 118u && e <= 132u);
  return __popcll(m) >= 32;
}
__device__ __forceinline__ float ldf(const void* p, size_t i, int isbf) {
  return isbf ? __bfloat162float(((const __hip_bfloat16*)p)[i]) : ((const float*)p)[i];
}
// f32 -> bf16 bits, RNE (finite inputs only)
__device__ __forceinline__ unsigned bfb(float f) {
  union { float f; unsigned u; } x; x.f = f;
  return (x.u + 0x7FFFu + ((x.u >> 16) & 1u)) >> 16;
}
__device__ __forceinline__ int pkbf(float a, float b) {
  return (int)(bfb(a) | (bfb(b) << 16));
}
// C-layout tile pair (m in [0,32)) -> A/B-frag (k=8q+j) via quad shuffles.
__device__ __forceinline__ s8v xform(int p00, int p01, int p10, int p11, int lane) {
  const int q = lane >> 4;
  const int sA = (lane & 15) + ((q & 1) << 5);
  const int sB = sA + 16;
  const bool hi = (q >> 1) != 0;
  const int w0a = __shfl(p00, sA), w0b = __shfl(p10, sA);
  const int w1a = __shfl(p01, sA), w1b = __shfl(p11, sA);
  const int w2a = __shfl(p00, sB), w2b = __shfl(p10, sB);
  const int w3a = __shfl(p01, sB), w3b = __shfl(p11, sB);
  union { int i[4]; s8v v; } u;
  u.i[0] = hi ? w0b : w0a;
  u.i[1] = hi ? w1b : w1a;
  u.i[2] = hi ? w2b : w2a;
  u.i[3] = hi ? w3b : w3a;
  return u.v;
}

__global__ __launch_bounds__(256) void prep_kernel(
    const void* __restrict__ x,
    const void* __restrict__ Wq, const void* __restrict__ bq,
    const void* __restrict__ Wk, const void* __restrict__ bk,
    const void* __restrict__ Wt, const void* __restrict__ bt,
    const int* __restrict__ sip, float* __restrict__ ws) {
  const int isbf = detect_is_bf16(x);
  const int al = blockIdx.x, a = al >> 2, li = al & 3;
  const int fq = blockIdx.y;  // f-quarter
  const int si = *sip;
  int off = 0;
  const int ATTR[5] = {3, 3, 1, 4, 3};
  for (int i = 0; i < si - 1 && i < 5; ++i) off += ATTR[i];
  const size_t wb = ((size_t)(off + a) * 5 + li) * 4096;
  const size_t bb = ((size_t)(off + a) * 5 + li) * 64;
  const int tid = threadIdx.x;

  __shared__ float sq[4096], sk[4096];
  __shared__ float sbq[64], sbk[64];
  for (int i = tid; i < 4096; i += 256) {
    sq[i] = ldf(Wq, wb + i, isbf);
    sk[i] = ldf(Wk, wb + i, isbf);
  }
  if (tid < 64) { sbq[tid] = ldf(bq, bb + tid, isbf); sbk[tid] = ldf(bk, bb + tid, isbf); }
  __syncthreads();

  __hip_bfloat16* mb  = (__hip_bfloat16*)((char*)ws + WSB_MB) + (size_t)al * 5120;
  __hip_bfloat16* wtb = (__hip_bfloat16*)((char*)ws + WSB_WT) + (size_t)al * 4096;

  for (int t = tid; t < 1024; t += 256) {
    const int f = fq * 16 + (t >> 6), f2 = t & 63;
    float acc = 0.f;
    #pragma unroll 16
    for (int g = 0; g < 64; ++g) acc += sk[g * 64 + f] * sq[g * 64 + f2];
    mb[f * 64 + f2] = __float2bfloat16(acc);                    // M[f][f2]
    wtb[f * 64 + f2] = __float2bfloat16(ldf(Wt, wb + f * 64 + f2, isbf));
  }
  if (fq == 0) {
    if (tid < 64) {
      float u = 0.f, v = 0.f;
      for (int g = 0; g < 64; ++g) {
        u += sq[g * 64 + tid] * sbk[g];
        v += sk[g * 64 + tid] * sbq[g];
      }
      mb[64 * 64 + tid] = __float2bfloat16(u);  // row 64 = u
      ws[al * 64 + tid] = v;
      ws[1024 + al * 64 + tid] = ldf(bt, bb + tid, isbf);
    }
    for (int i = tid; i < 15 * 64; i += 256) mb[65 * 64 + i] = __float2bfloat16(0.f);
    if (tid == 0) {
      float c = 0.f;
      for (int g = 0; g < 64; ++g) c += sbq[g] * sbk[g];
      ws[2048 + al] = c;
    }
  }
}

__global__ __launch_bounds__(256) void attn_kernel(
    const void* __restrict__ x, const float* __restrict__ ws,
    float* __restrict__ out) {
  const int isbf = detect_is_bf16(x);
  const int chunk = blockIdx.x;   // 0..31
  const int ba = blockIdx.y;      // b*4 + a
  const int b = ba >> 2, a = ba & 3;
  const int s0 = chunk * 64;
  const int tid = threadIdx.x;
  const int lane = tid & 63;
  const int mt = tid >> 6;        // wave = 16-row m-tile
  const int c16 = lane & 15;
  const int q = lane >> 4;

  __shared__ __align__(16) char lds[LDS_TOTAL];

  // ---- stage Y window (both orientations) + rowflags; one barrier ----
  #pragma unroll
  for (int it = 0; it < 7; ++it) {
    const int r = it * 16 + (tid >> 4);   // 0..111
    const int j = s0 - KWIN + r;
    float4 yv = {0.f, 0.f, 0.f, 0.f};
    if (r < 104 && j >= 0 && j < SDIM) {
      if (isbf) {
        const size_t base = (((size_t)b * SDIM + j) * 4 + a) * 64 + c16 * 4;
        yv.x = ldf(x, base, 1); yv.y = ldf(x, base + 1, 1);
        yv.z = ldf(x, base + 2, 1); yv.w = ldf(x, base + 3, 1);
      } else {
        yv = *((const float4*)x + (((size_t)b * SDIM + j) * 4 + a) * 16 + c16);
      }
    }
    const int f0 = c16 * 4;
    ((int*)(lds + O_YJF + r * 144 + f0 * 2))[0] = pkbf(yv.x, yv.y);
    ((int*)(lds + O_YJF + r * 144 + f0 * 2))[1] = pkbf(yv.z, yv.w);
    *(unsigned short*)(lds + O_YFJ + (f0 + 0) * 240 + r * 2) = (unsigned short)bfb(yv.x);
    *(unsigned short*)(lds + O_YFJ + (f0 + 1) * 240 + r * 2) = (unsigned short)bfb(yv.y);
    *(unsigned short*)(lds + O_YFJ + (f0 + 2) * 240 + r * 2) = (unsigned short)bfb(yv.z);
    *(unsigned short*)(lds + O_YFJ + (f0 + 3) * 240 + r * 2) = (unsigned short)bfb(yv.w);
    const bool nz = (yv.x != 0.f) || (yv.y != 0.f) || (yv.z != 0.f) || (yv.w != 0.f);
    const unsigned long long m = __ballot(nz);
    if (c16 == 0) ((float*)(lds + O_RF))[r] = ((m >> (q * 16)) & 0xFFFFull) ? 1.f : 0.f;
  }
  __syncthreads();

  const short* mbase  = (const short*)((const char*)ws + WSB_MB);
  const short* wtbase = (const short*)((const char*)ws + WSB_WT);
  const char* yjf = lds + O_YJF;
  const char* yfj = lds + O_YFJ;

  // level-invariant: X^T B-frag (query rows), rowflags for own band
  const s8v xb0 = *(const s8v*)(yjf + (KWIN + 16 * mt + c16) * 144 + 16 * q);
  const s8v xb1 = *(const s8v*)(yjf + (KWIN + 16 * mt + c16) * 144 + 64 + 16 * q);
  float rfarr[16];
  #pragma unroll
  for (int nt = 0; nt < 4; ++nt) {
    const float4 t = *(const float4*)((const float*)(lds + O_RF) + 16 * mt + 16 * nt + 4 * q);
    rfarr[nt * 4 + 0] = t.x; rfarr[nt * 4 + 1] = t.y;
    rfarr[nt * 4 + 2] = t.z; rfarr[nt * 4 + 3] = t.w;
  }

  for (int l = 0; l < 4; ++l) {
    const int al = a * 4 + l;
    const short* mb  = mbase + (size_t)al * 5120;
    const short* wtb = wtbase + (size_t)al * 4096;
    const float c_al = ws[2048 + al];

    // ===== G1 (swapped): QK^T = M * X^T (+v); m-tile 4 = u-row =====
    int pq[4][2];
    f32x4 uacc = {0.f, 0.f, 0.f, 0.f};
    #pragma unroll
    for (int nt = 0; nt < 5; ++nt) {
      const int rowm = (nt < 4) ? (16 * nt + c16) : (64 + c16);
      const s8v a0 = *(const s8v*)(mb + rowm * 64 + 8 * q);
      const s8v a1 = *(const s8v*)(mb + rowm * 64 + 32 + 8 * q);
      f32x4 acc;
      if (nt < 4) {
        const float4 v4 = *(const float4*)(ws + al * 64 + 16 * nt + 4 * q);
        acc[0] = v4.x; acc[1] = v4.y; acc[2] = v4.z; acc[3] = v4.w;
      } else {
        acc[0] = acc[1] = acc[2] = acc[3] = 0.f;
      }
      acc = MFMA(a0, xb0, acc, 0, 0, 0);
      acc = MFMA(a1, xb1, acc, 0, 0, 0);
      if (nt < 4) { pq[nt][0] = pkbf(acc[0], acc[1]); pq[nt][1] = pkbf(acc[2], acc[3]); }
      else uacc = acc;
    }
    const float ux = __shfl(uacc[0], lane & 15) + c_al;  // u.x for row=c16
    const s8v qb0 = xform(pq[0][0], pq[0][1], pq[1][0], pq[1][1], lane);
    const s8v qb1 = xform(pq[2][0], pq[2][1], pq[3][0], pq[3][1], lane);

    // ===== G2 (swapped): S^T = Y * QK^T ; D[j][row] =====
    f32x4 st[4];
    #pragma unroll
    for (int nt = 0; nt < 4; ++nt) {
      const char* yr = yjf + (16 * mt + 16 * nt + c16) * 144 + 16 * q;
      const s8v a0 = *(const s8v*)yr;
      const s8v a1 = *(const s8v*)(yr + 64);
      f32x4 s = {0.f, 0.f, 0.f, 0.f};
      s = MFMA(a0, qb0, s, 0, 0, 0);
      s = MFMA(a1, qb1, s, 0, 0, 0);
      st[nt] = s;
    }

    // ===== softmax in registers (row = c16, j spread over nt/q/r) =====
    float ee[16];
    float mx = -3.0e38f;
    #pragma unroll
    for (int nt = 0; nt < 4; ++nt)
      #pragma unroll
      for (int r = 0; r < 4; ++r) {
        const int w = 16 * nt + 4 * q + r - c16;
        float lv = -1.0e9f;
        if (w >= 0 && w < WWIN && rfarr[nt * 4 + r] != 0.f)
          lv = (st[nt][r] + ux) * 0.125f;
        ee[nt * 4 + r] = lv;
        mx = fmaxf(mx, lv);
      }
    mx = fmaxf(mx, __shfl_xor(mx, 16));
    mx = fmaxf(mx, __shfl_xor(mx, 32));
    float se = 0.f;
    #pragma unroll
    for (int i = 0; i < 16; ++i) { ee[i] = __expf(ee[i] - mx); se += ee[i]; }
    se += __shfl_xor(se, 16);
    se += __shfl_xor(se, 32);
    const float rse = 1.f / se;

    int pp[4][2];
    #pragma unroll
    for (int nt = 0; nt < 4; ++nt) {
      pp[nt][0] = pkbf(ee[nt * 4 + 0], ee[nt * 4 + 1]);
      pp[nt][1] = pkbf(ee[nt * 4 + 2], ee[nt * 4 + 3]);
    }
    const s8v pb0 = xform(pp[0][0], pp[0][1], pp[1][0], pp[1][1], lane);
    const s8v pb1 = xform(pp[2][0], pp[2][1], pp[3][0], pp[3][1], lane);

    // ===== G3 (swapped): CTX^T = Y^T * P ; scale by rse =====
    int cp[4][2];
    #pragma unroll
    for (int nt = 0; nt < 4; ++nt) {
      const char* fr = yfj + (16 * nt + c16) * 240 + 32 * mt + 16 * q;
      const s8v a0 = *(const s8v*)fr;
      const s8v a1 = *(const s8v*)(fr + 64);
      f32x4 cc = {0.f, 0.f, 0.f, 0.f};
      cc = MFMA(a0, pb0, cc, 0, 0, 0);
      cc = MFMA(a1, pb1, cc, 0, 0, 0);
      cp[nt][0] = pkbf(cc[0] * rse, cc[1] * rse);
      cp[nt][1] = pkbf(cc[2] * rse, cc[3] * rse);
    }
    // cb = B-frag of CTX^T == A-frag of CTX (identical lane content)
    const s8v cb0 = xform(cp[0][0], cp[0][1], cp[1][0], cp[1][1], lane);
    const s8v cb1 = xform(cp[2][0], cp[2][1], cp[3][0], cp[3][1], lane);

    // ===== G4 (UNswapped): OUT = CTX * Wt^T + bt ; C-layout D ->
    //       16 consecutive lanes write 64 consecutive floats (coalesced) =====
    #pragma unroll
    for (int nt = 0; nt < 4; ++nt) {
      // B-frag: lane holds Wt[g=16nt+c16][f=8q+i] == Wt^T[k=f][n=g]
      const s8v b0 = *(const s8v*)(wtb + (16 * nt + c16) * 64 + 8 * q);
      const s8v b1 = *(const s8v*)(wtb + (16 * nt + c16) * 64 + 32 + 8 * q);
      const float btv = ws[1024 + al * 64 + 16 * nt + c16];  // bt[g], same for all r
      f32x4 o = {btv, btv, btv, btv};
      o = MFMA(cb0, b0, o, 0, 0, 0);
      o = MFMA(cb1, b1, o, 0, 0, 0);
      // D[m=4q+r][n=c16]: s-row = s0+16mt+4q+r, g = 16nt+c16
      float* op = out + ((((size_t)b * SDIM + (s0 + 16 * mt + 4 * q)) * 4 + a) * 4 + l) * 64
                  + 16 * nt + c16;
      #pragma unroll
      for (int r = 0; r < 4; ++r) op[(size_t)r * 1024] = o[r];
    }
  }
}

extern "C" void kernel_launch(void* const* d_in, const int* in_sizes, int n_in,
                              void* d_out, int out_size, void* d_ws, size_t ws_size,
                              hipStream_t stream) {
  const void* x  = d_in[0];
  const void* Wq = d_in[1];
  const void* bq = d_in[2];
  const void* Wk = d_in[3];
  const void* bk = d_in[4];
  const void* Wt = d_in[5];
  const void* bt = d_in[6];
  const int* sip = (const int*)d_in[7];
  float* ws = (float*)d_ws;
  float* out = (float*)d_out;

  prep_kernel<<<dim3(16, 4), 256, 0, stream>>>(x, Wq, bq, Wk, bk, Wt, bt, sip, ws);
  attn_kernel<<<dim3(32, 16), 256, 0, stream>>>(x, ws, out);
}